// Round 3
// baseline (600.093 us; speedup 1.0000x reference)
//
#include <hip/hip_runtime.h>
#include <hip/hip_bf16.h>
#include <math.h>

// Problem shape: B=1024, N=256, D=512, fp32.
// out = log(pos + neg) - log(pos)
//   pos = sum_b exp(dot(normalize(img[b]), fg_pro[b]))
//   neg = sum_{b,n} exp(dot(normalize(img[b]), bg_pro[b][n]))
// bg_pro = 512 MiB streamed once -> ~86 us kernel floor at 6.3 TB/s.
//
// R6: strip main to a PURE stream. The normalize+pos prologue (2 barriers,
// butterfly, LDS round-trip, divergent split==0 path) ran in all 16384
// blocks of R5, diluting load-issue duty cycle. Now:
//   k1 infonce_norm  (256 blocks): img_norm[b] = img[b]/||img[b]||,
//                                  pos[b] = exp(dot(img_norm,fg_pro)).  ~3us
//   k2 infonce_main  (16384 blocks): 2 L2-hit img_norm loads + 8 bg loads
//                                  + dots + tail reduce. No barrier before
//                                  the tail, no divergence, ~60 VGPR.
//   k3 infonce_finalize: reduce 16384+1024 partials, compose the loss.
// Workspace: neg[16384] | pos[1024] | img_norm[1024*512]  (~2.1 MiB).

#define D_DIM   512
#define NSPLIT  16                // blocks per batch row
#define ROWS_PER_WAVE 4           // (N / NSPLIT) / 4 waves

__global__ __launch_bounds__(256) void infonce_norm(
    const float* __restrict__ img,      // [B, D]
    const float* __restrict__ fg_pro,   // [B, D]
    float* __restrict__ img_norm,       // [B, D]
    float* __restrict__ pos_out,        // [B]
    int B)
{
    const int row  = blockIdx.x * 4 + (threadIdx.x >> 6);  // one wave per row
    const int lane = threadIdx.x & 63;
    if (row >= B) return;

    const float4* img4 = reinterpret_cast<const float4*>(img) + (size_t)row * (D_DIM / 4);
    const float4 a0 = img4[lane];
    const float4 a1 = img4[64 + lane];

    float ss = a0.x*a0.x + a0.y*a0.y + a0.z*a0.z + a0.w*a0.w
             + a1.x*a1.x + a1.y*a1.y + a1.z*a1.z + a1.w*a1.w;
    #pragma unroll
    for (int off = 32; off > 0; off >>= 1) ss += __shfl_xor(ss, off);
    const float inv = rsqrtf(ss);

    const float4 n0 = make_float4(a0.x*inv, a0.y*inv, a0.z*inv, a0.w*inv);
    const float4 n1 = make_float4(a1.x*inv, a1.y*inv, a1.z*inv, a1.w*inv);

    float4* out4 = reinterpret_cast<float4*>(img_norm) + (size_t)row * (D_DIM / 4);
    out4[lane]      = n0;
    out4[64 + lane] = n1;

    const float4* fg4 = reinterpret_cast<const float4*>(fg_pro) + (size_t)row * (D_DIM / 4);
    const float4 f0 = fg4[lane];
    const float4 f1 = fg4[64 + lane];
    float pd = n0.x*f0.x + n0.y*f0.y + n0.z*f0.z + n0.w*f0.w
             + n1.x*f1.x + n1.y*f1.y + n1.z*f1.z + n1.w*f1.w;
    #pragma unroll
    for (int off = 32; off > 0; off >>= 1) pd += __shfl_xor(pd, off);
    if (lane == 0) pos_out[row] = expf(pd);
}

__global__ __launch_bounds__(256, 4) void infonce_main(
    const float* __restrict__ img_norm, // [B, D] (normalized)
    const float* __restrict__ bg_pro,   // [B, N, D]
    float* __restrict__ neg_out,        // [B*NSPLIT]
    int N)
{
    const int bid   = blockIdx.x;
    const int b     = bid >> 4;               // NSPLIT == 16
    const int split = bid & 15;
    const int tid   = threadIdx.x;
    const int wid   = tid >> 6;
    const int lane  = tid & 63;

    // img_norm row: 2 KiB shared by 16 blocks -> L2 hits. No LDS, no barrier.
    const float4* in4 = reinterpret_cast<const float4*>(img_norm) + (size_t)b * (D_DIM / 4);
    const float4 a0 = in4[lane];
    const float4 a1 = in4[64 + lane];

    const int n0 = split * (N / NSPLIT) + wid * ROWS_PER_WAVE;
    const float4* bg4 = reinterpret_cast<const float4*>(
        bg_pro + (size_t)b * N * D_DIM + (size_t)n0 * D_DIM);

    const float4* r0 = bg4;
    const float4* r1 = bg4 + 1 * (D_DIM / 4);
    const float4* r2 = bg4 + 2 * (D_DIM / 4);
    const float4* r3 = bg4 + 3 * (D_DIM / 4);
    const float4 b00 = r0[lane], b01 = r0[64 + lane];
    const float4 b10 = r1[lane], b11 = r1[64 + lane];
    const float4 b20 = r2[lane], b21 = r2[64 + lane];
    const float4 b30 = r3[lane], b31 = r3[64 + lane];

    float d0 = a0.x*b00.x + a0.y*b00.y + a0.z*b00.z + a0.w*b00.w
             + a1.x*b01.x + a1.y*b01.y + a1.z*b01.z + a1.w*b01.w;
    float d1 = a0.x*b10.x + a0.y*b10.y + a0.z*b10.z + a0.w*b10.w
             + a1.x*b11.x + a1.y*b11.y + a1.z*b11.z + a1.w*b11.w;
    float d2 = a0.x*b20.x + a0.y*b20.y + a0.z*b20.z + a0.w*b20.w
             + a1.x*b21.x + a1.y*b21.y + a1.z*b21.z + a1.w*b21.w;
    float d3 = a0.x*b30.x + a0.y*b30.y + a0.z*b30.z + a0.w*b30.w
             + a1.x*b31.x + a1.y*b31.y + a1.z*b31.z + a1.w*b31.w;

    #pragma unroll
    for (int off = 32; off > 0; off >>= 1) {
        d0 += __shfl_xor(d0, off);
        d1 += __shfl_xor(d1, off);
        d2 += __shfl_xor(d2, off);
        d3 += __shfl_xor(d3, off);
    }

    __shared__ float s_red[4];
    if (lane == 0)
        s_red[wid] = expf(d0) + expf(d1) + expf(d2) + expf(d3);
    __syncthreads();
    if (tid == 0)
        neg_out[bid] = s_red[0] + s_red[1] + s_red[2] + s_red[3];
}

__global__ __launch_bounds__(256) void infonce_finalize(
    const float* __restrict__ part, float* __restrict__ out,
    int nneg, int npos)
{
    const int tid = threadIdx.x;
    float neg = 0.0f, pos = 0.0f;
    for (int i = tid; i < nneg; i += 256) neg += part[i];
    for (int i = tid; i < npos; i += 256) pos += part[nneg + i];
    #pragma unroll
    for (int off = 32; off > 0; off >>= 1) {
        neg += __shfl_xor(neg, off);
        pos += __shfl_xor(pos, off);
    }
    __shared__ float sn[4], sp[4];
    if ((tid & 63) == 0) { sn[tid >> 6] = neg; sp[tid >> 6] = pos; }
    __syncthreads();
    if (tid == 0) {
        const float P = sp[0] + sp[1] + sp[2] + sp[3];
        const float Ntot = sn[0] + sn[1] + sn[2] + sn[3];
        out[0] = logf(P + Ntot) - logf(P);   // == -log(pos/(pos+neg))
    }
}

extern "C" void kernel_launch(void* const* d_in, const int* in_sizes, int n_in,
                              void* d_out, int out_size, void* d_ws, size_t ws_size,
                              hipStream_t stream)
{
    const float* img = (const float*)d_in[0];   // [B, D]
    const float* fg  = (const float*)d_in[1];   // [B, D]
    const float* bg  = (const float*)d_in[2];   // [B, N, D]
    float* out = (float*)d_out;

    const int B = in_sizes[0] / (D_DIM * (int)sizeof(float));
    const int N = in_sizes[2] / in_sizes[0];

    float* neg      = (float*)d_ws;             // [B*NSPLIT]
    float* pos      = neg + (size_t)B * NSPLIT; // [B]
    float* img_norm = pos + B;                  // [B*D], 16B-aligned (17408*4)

    infonce_norm<<<B / 4, 256, 0, stream>>>(img, fg, img_norm, pos, B);
    infonce_main<<<B * NSPLIT, 256, 0, stream>>>(img_norm, bg, neg, N);
    infonce_finalize<<<1, 256, 0, stream>>>(neg, out, B * NSPLIT, B);
}